// Round 5
// baseline (353.946 us; speedup 1.0000x reference)
//
#include <hip/hip_runtime.h>
#include <hip/hip_bf16.h>

// ---------------------------------------------------------------------------
// TileSelfAttention, round 5.
// QKV GEMM: dual-digit int8 MFMA (exact i32 acc).
//   A (X) staged in FRAGMENT-ORDER LDS (tile*1024 + lane*16) -> every
//   ds_read_b128 is wave-sequential => zero bank conflicts. Ring-4 buffers,
//   stage depth 3, counted vmcnt (never drains in main loop).
//   B (W, 3MB, L2-resident) loaded DIRECT to registers from fragment-tiled
//   W (quant_w pre-tiles) -> B's LDS write+read traffic eliminated.
// Softmax: stats kernel writes m/inv tables; out_kernel applies exp inline.
// ---------------------------------------------------------------------------

typedef __bf16 bf16;
using i32x4 = __attribute__((ext_vector_type(4))) int;

#define NT     64
#define BATCH  512

#define OFF_XQH 0ul
#define OFF_XQL 33554432ul
#define OFF_WT  67108864ul
#define OFF_K   70254592ul
#define OFF_Q   137363456ul
#define OFF_V   204472320ul
#define OFF_AW  271581184ul
#define OFF_MS  279969792ul

// ---------------------------------------------------------------------------
// quantize x: fp32 -> (qh, ql) int8 digit planes, row-major.
// ---------------------------------------------------------------------------
__global__ void quant_kernel(const float* __restrict__ x,
                             unsigned int* __restrict__ qh,
                             unsigned int* __restrict__ ql, int n4, float invS) {
  int i = blockIdx.x * blockDim.x + threadIdx.x;
  int stride = gridDim.x * blockDim.x;
  for (; i < n4; i += stride) {
    float4 v = ((const float4*)x)[i];
    unsigned hw = 0, lw = 0;
#pragma unroll
    for (int j = 0; j < 4; ++j) {
      float f = (j == 0) ? v.x : (j == 1) ? v.y : (j == 2) ? v.z : v.w;
      int q = __float2int_rn(f * invS);
      q = max(-16320, min(16319, q));
      int h = (q + 64) >> 7;
      int lo = q - (h << 7);
      hw |= ((unsigned)(h & 0xFF)) << (8 * j);
      lw |= ((unsigned)(lo & 0xFF)) << (8 * j);
    }
    qh[i] = hw;
    ql[i] = lw;
  }
}

// ---------------------------------------------------------------------------
// quantize W into fragment-tiled layout:
//   WT[proj] : offset = ((ct*16 + kc)*2048) + plane*1024 + lane*16 + ki
//   ct = c>>4 (16-col tile), kc = k>>6, lane = (c&15) | (((k>>4)&3)<<4),
//   ki = k&15.  plane 0 = ph (high digit), 1 = pl (low digit).
// ---------------------------------------------------------------------------
__global__ void quant_w_kernel(const float* __restrict__ W,
                               char* __restrict__ WT, float invS) {
  int idx = blockIdx.x * blockDim.x + threadIdx.x;  // 0..131071
  if (idx >= 131072) return;
  int c = idx >> 8, k = (idx & 255) * 4;
  float4 v = ((const float4*)W)[idx];
  unsigned hw = 0, lw = 0;
#pragma unroll
  for (int j = 0; j < 4; ++j) {
    float f = (j == 0) ? v.x : (j == 1) ? v.y : (j == 2) ? v.z : v.w;
    int q = __float2int_rn(f * invS);
    q = max(-16320, min(16319, q));
    int h = (q + 64) >> 7;
    int lo = q - (h << 7);
    hw |= ((unsigned)(h & 0xFF)) << (8 * j);
    lw |= ((unsigned)(lo & 0xFF)) << (8 * j);
  }
  int kc = k >> 6, kg = (k >> 4) & 3, ki = k & 15;
  int ct = c >> 4, lane = (c & 15) | (kg << 4);
  size_t dst = (size_t)(ct * 16 + kc) * 2048 + lane * 16 + ki;
  *(unsigned int*)(WT + dst) = hw;          // ph plane
  *(unsigned int*)(WT + dst + 1024) = lw;   // pl plane
}

// ---------------------------------------------------------------------------
__device__ __forceinline__ void gl16(const char* g, char* l) {
  __builtin_amdgcn_global_load_lds(
      (const __attribute__((address_space(1))) unsigned int*)g,
      (__attribute__((address_space(3))) unsigned int*)l, 16, 0, 0);
}

#define VMCNT(n) asm volatile("s_waitcnt vmcnt(" #n ")" ::: "memory")
#define BAR      __builtin_amdgcn_s_barrier()

__global__ __launch_bounds__(512, 2) void gemm_i8(
    const char* __restrict__ XQH, const char* __restrict__ XQL,
    const char* __restrict__ WT,
    const float* __restrict__ bk, const float* __restrict__ bq,
    const float* __restrict__ bv,
    float* __restrict__ K, float* __restrict__ Q, float* __restrict__ V) {
  __shared__ __align__(16) char lds[65536];  // ring of 4 x 16KB (A only)

  // T1: bijective XCD swizzle (1536 = 8 * 192)
  const int bid = (blockIdx.x & 7) * 192 + (blockIdx.x >> 3);
  const int mt = bid / 6, ntb = bid % 6;
  const int gm0 = mt * 128;
  const int proj = ntb >> 1;
  const int wn0 = (ntb & 1) * 256;

  const int tid = threadIdx.x;
  const int l = tid & 63, w = tid >> 6;
  const int wr = w >> 2, wc = w & 3;  // 2M x 4N waves, wave tile 64x64
  const int lr = l & 15, lk = l >> 4;

  // A staging: thread tid stages 16B of each plane per chunk.
  //   LDS slot tid*16  <-  X[gm0 + (tid>>6)*16 + (tid&15)][kc*64 + ((tid>>4)&3)*16 ..]
  const int srow = ((tid >> 6) << 4) | (tid & 15);
  const int skk = ((tid >> 4) & 3) << 4;
  const char* aqh = XQH + (size_t)(gm0 + srow) * 1024 + skk;
  const char* aql = XQL + (size_t)(gm0 + srow) * 1024 + skk;
  const int dqh = tid * 16, dql = 8192 + tid * 16;

  // A fragment reads: tile (wr*4+mf), lane-sequential
  const int rdA = (wr * 4) * 1024 + l * 16;

  // B direct loads from tiled W: ct = wn0/16 + wc*4 + nf
  const char* wbase = WT + (size_t)proj * 1048576 +
                      (size_t)((ntb & 1) * 16 + wc * 4) * 32768 + l * 16;

  i32x4 acc1[4][4] = {};
  i32x4 acc2[4][4] = {};

  auto STAGE = [&](int kc) {
    const int bo = (kc & 3) * 16384;
    gl16(aqh + kc * 64, lds + bo + dqh);
    gl16(aql + kc * 64, lds + bo + dql);
  };

  STAGE(0); STAGE(1); STAGE(2);

  for (int kc = 0; kc < 16; ++kc) {
    if (kc < 14) { VMCNT(4); }
    else if (kc == 14) { VMCNT(2); }
    else { VMCNT(0); }
    BAR;
    __builtin_amdgcn_sched_barrier(0);
    if (kc <= 12) STAGE(kc + 3);

    const int bo = (kc & 3) * 16384;
    const char* wkc = wbase + kc * 2048;
    i32x4 bL[4], bH[4], aH[4], aL[4];
#pragma unroll
    for (int nf = 0; nf < 4; ++nf)
      bL[nf] = *(const i32x4*)(wkc + nf * 32768 + 1024);
#pragma unroll
    for (int nf = 0; nf < 4; ++nf)
      bH[nf] = *(const i32x4*)(wkc + nf * 32768);
#pragma unroll
    for (int mf = 0; mf < 4; ++mf)
      aH[mf] = *(const i32x4*)(lds + bo + rdA + mf * 1024);
#pragma unroll
    for (int mf = 0; mf < 4; ++mf)
      aL[mf] = *(const i32x4*)(lds + bo + 8192 + rdA + mf * 1024);

    __builtin_amdgcn_s_setprio(1);
#pragma unroll
    for (int mf = 0; mf < 4; ++mf)   // alpha: qh . pl -> acc2
#pragma unroll
      for (int nf = 0; nf < 4; ++nf)
        acc2[mf][nf] = __builtin_amdgcn_mfma_i32_16x16x64_i8(
            aH[mf], bL[nf], acc2[mf][nf], 0, 0, 0);
#pragma unroll
    for (int mf = 0; mf < 4; ++mf)   // beta: qh . ph -> acc1 (reuse aH)
#pragma unroll
      for (int nf = 0; nf < 4; ++nf)
        acc1[mf][nf] = __builtin_amdgcn_mfma_i32_16x16x64_i8(
            aH[mf], bH[nf], acc1[mf][nf], 0, 0, 0);
#pragma unroll
    for (int mf = 0; mf < 4; ++mf)   // gamma: ql . ph -> acc2 (reuse bH)
#pragma unroll
      for (int nf = 0; nf < 4; ++nf)
        acc2[mf][nf] = __builtin_amdgcn_mfma_i32_16x16x64_i8(
            aL[mf], bH[nf], acc2[mf][nf], 0, 0, 0);
    __builtin_amdgcn_s_setprio(0);
  }

  // epilogue: Out = XS*WS*(16384*acc1 + 128*acc2) + bias
  const float SC = (6.0f / 16256.0f) * (0.03125f / 16320.0f);
  const float* bias = (proj == 0) ? bk : (proj == 1 ? bq : bv);
  float* Out = (proj == 0) ? K : (proj == 1 ? Q : V);
#pragma unroll
  for (int mf = 0; mf < 4; ++mf) {
    const int row0 = gm0 + wr * 64 + mf * 16 + lk * 4;
#pragma unroll
    for (int nf = 0; nf < 4; ++nf) {
      const int col = wn0 + wc * 64 + nf * 16 + lr;
      const float bb = bias[col];
#pragma unroll
      for (int r = 0; r < 4; ++r)
        Out[(size_t)(row0 + r) * 512 + col] =
            fmaf(16384.f, (float)acc1[mf][nf][r],
                 128.f * (float)acc2[mf][nf][r]) * SC + bb;
    }
  }
}

// ---------------------------------------------------------------------------
// logits: AW[b,t,s] = (1/sqrt(512)) * sum_c K[b*64+t,c] * Q[b*64+s,c]
// ---------------------------------------------------------------------------
__global__ __launch_bounds__(256) void logits_kernel(
    const float* __restrict__ K, const float* __restrict__ Q,
    float* __restrict__ AW) {
  __shared__ float Ks[64][68];
  __shared__ float Qs[64][68];
  const int b = blockIdx.x;
  const float* Kb = K + (size_t)b * 32768;
  const float* Qb = Q + (size_t)b * 32768;
  const int tid = threadIdx.x;
  const int tr = tid >> 4, tc = tid & 15;

  float acc[4][4] = {};
  for (int c0 = 0; c0 < 512; c0 += 64) {
    __syncthreads();
#pragma unroll
    for (int i = 0; i < 4; ++i) {
      int idx = tid + i * 256;
      int row = idx >> 4;
      int c4 = (idx & 15) * 4;
      float4 kv = *(const float4*)&Kb[row * 512 + c0 + c4];
      float4 qv = *(const float4*)&Qb[row * 512 + c0 + c4];
      Ks[c4 + 0][row] = kv.x; Ks[c4 + 1][row] = kv.y;
      Ks[c4 + 2][row] = kv.z; Ks[c4 + 3][row] = kv.w;
      Qs[c4 + 0][row] = qv.x; Qs[c4 + 1][row] = qv.y;
      Qs[c4 + 2][row] = qv.z; Qs[c4 + 3][row] = qv.w;
    }
    __syncthreads();
#pragma unroll 4
    for (int cc = 0; cc < 64; ++cc) {
      float4 kx = *(const float4*)&Ks[cc][tr * 4];
      float4 qx = *(const float4*)&Qs[cc][tc * 4];
#pragma unroll
      for (int i = 0; i < 4; ++i)
#pragma unroll
        for (int j = 0; j < 4; ++j) acc[i][j] += kx[i] * qx[j];
    }
  }
  const float scale = 0.04419417382415922f;
#pragma unroll
  for (int i = 0; i < 4; ++i)
#pragma unroll
    for (int j = 0; j < 4; ++j)
      AW[(size_t)b * 4096 + (tr * 4 + i) * 64 + (tc * 4 + j)] =
          acc[i][j] * scale;
}

// ---------------------------------------------------------------------------
// stats over batch axis: for each (t,s), m = max_b, inv = 1/sum_b exp(l-m).
// grid 64 (t), 1024 threads = (s 0..63) x (b-16th 0..15).
// ---------------------------------------------------------------------------
__global__ __launch_bounds__(1024) void stats_kernel(
    const float* __restrict__ AW, float* __restrict__ M,
    float* __restrict__ I) {
  __shared__ float red[16][64];
  const int tt = blockIdx.x;
  const int tid = threadIdx.x;
  const int s = tid & 63, bq = tid >> 6;
  const size_t base = (size_t)tt * 64 + s;

  float m = -3.4e38f;
  for (int b = bq * 32; b < bq * 32 + 32; ++b)
    m = fmaxf(m, AW[(size_t)b * 4096 + base]);
  red[bq][s] = m;
  __syncthreads();
#pragma unroll
  for (int i = 0; i < 16; ++i) m = fmaxf(m, red[i][s]);
  __syncthreads();

  float sum = 0.f;
  for (int b = bq * 32; b < bq * 32 + 32; ++b)
    sum += __expf(AW[(size_t)b * 4096 + base] - m);
  red[bq][s] = sum;
  __syncthreads();
  if (bq == 0) {
    sum = 0.f;
#pragma unroll
    for (int i = 0; i < 16; ++i) sum += red[i][s];
    M[tt * 64 + s] = m;
    I[tt * 64 + s] = 1.0f / sum;
  }
}

// ---------------------------------------------------------------------------
// out[b,c,s] = sum_t V[b*64+t, c] * p,  p = exp(AW[b,t,s]-M[t,s])*I[t,s]
// ---------------------------------------------------------------------------
__global__ __launch_bounds__(256) void out_kernel(
    const float* __restrict__ V, const float* __restrict__ AW,
    const float* __restrict__ M, const float* __restrict__ I,
    float* __restrict__ out) {
  __shared__ float Ps[64][68];
  __shared__ float Vs[64][68];
  const int b = blockIdx.x;
  const int tid = threadIdx.x;
  const float* Pb = AW + (size_t)b * 4096;
  for (int i = tid; i < 4096; i += 256)
    Ps[i >> 6][i & 63] = __expf(Pb[i] - M[i]) * I[i];

  const int s = tid & 63, cw = tid >> 6;
  const float* Vb = V + (size_t)b * 32768;
  float* Ob = out + (size_t)b * 32768;

  for (int ch = 0; ch < 8; ++ch) {
    __syncthreads();
    for (int i = tid; i < 1024; i += 256) {
      int row = i >> 4, c4 = (i & 15) * 4;
      float4 v = *(const float4*)&Vb[(size_t)row * 512 + ch * 64 + c4];
      Vs[row][c4 + 0] = v.x; Vs[row][c4 + 1] = v.y;
      Vs[row][c4 + 2] = v.z; Vs[row][c4 + 3] = v.w;
    }
    __syncthreads();
    float a[16] = {};
    for (int t = 0; t < 64; ++t) {
      float p = Ps[t][s];
      float4 v0 = *(const float4*)&Vs[t][cw * 16 + 0];
      float4 v1 = *(const float4*)&Vs[t][cw * 16 + 4];
      float4 v2 = *(const float4*)&Vs[t][cw * 16 + 8];
      float4 v3 = *(const float4*)&Vs[t][cw * 16 + 12];
#pragma unroll
      for (int j = 0; j < 4; ++j) {
        a[j + 0] += v0[j] * p; a[j + 4] += v1[j] * p;
        a[j + 8] += v2[j] * p; a[j + 12] += v3[j] * p;
      }
    }
#pragma unroll
    for (int j = 0; j < 16; ++j)
      Ob[(size_t)(ch * 64 + cw * 16 + j) * 64 + s] = a[j];
  }
}

// ---------------------------------------------------------------------------
extern "C" void kernel_launch(void* const* d_in, const int* in_sizes, int n_in,
                              void* d_out, int out_size, void* d_ws,
                              size_t ws_size, hipStream_t stream) {
  const float* x  = (const float*)d_in[0];
  const float* Wk = (const float*)d_in[1];
  const float* bk = (const float*)d_in[2];
  const float* Wq = (const float*)d_in[3];
  const float* bq = (const float*)d_in[4];
  const float* Wv = (const float*)d_in[5];
  const float* bv = (const float*)d_in[6];
  float* out = (float*)d_out;

  char* ws = (char*)d_ws;
  unsigned int* XQH = (unsigned int*)(ws + OFF_XQH);
  unsigned int* XQL = (unsigned int*)(ws + OFF_XQL);
  char* WT = ws + OFF_WT;
  float* K  = (float*)(ws + OFF_K);
  float* Q  = (float*)(ws + OFF_Q);
  float* V  = (float*)(ws + OFF_V);
  float* AW = (float*)(ws + OFF_AW);
  float* M  = (float*)(ws + OFF_MS);
  float* I  = (float*)(ws + OFF_MS + 16384);

  const float invXS = 16256.0f / 6.0f;
  const float invWS = 16320.0f / 0.03125f;

  quant_kernel<<<2048, 256, 0, stream>>>(x, XQH, XQL, 8388608, invXS);
  quant_w_kernel<<<512, 256, 0, stream>>>(Wk, WT + 0ul * 1048576ul, invWS);
  quant_w_kernel<<<512, 256, 0, stream>>>(Wq, WT + 1ul * 1048576ul, invWS);
  quant_w_kernel<<<512, 256, 0, stream>>>(Wv, WT + 2ul * 1048576ul, invWS);

  gemm_i8<<<1536, 512, 0, stream>>>((const char*)XQH, (const char*)XQL,
                                    WT, bk, bq, bv, K, Q, V);

  logits_kernel<<<BATCH, 256, 0, stream>>>(K, Q, AW);
  stats_kernel<<<NT, 1024, 0, stream>>>(AW, M, I);
  out_kernel<<<BATCH, 256, 0, stream>>>(V, AW, M, I, out);
}

// Round 6
// 311.569 us; speedup vs baseline: 1.1360x; 1.1360x over previous
//
#include <hip/hip_runtime.h>
#include <hip/hip_bf16.h>

// ---------------------------------------------------------------------------
// TileSelfAttention, round 6.
// QKV GEMM: dual-digit int8 MFMA (exact i32 acc).
//   R4's pipeline (double-buffer LDS, 1 barrier + 1 vmcnt(0) per K=64 chunk,
//   stage issued a full chunk ahead) + R5's zero-conflict FRAGMENT-ORDER LDS
//   for BOTH A and B (B staged from pre-tiled WT via linear gl16).
//   Every ds_read_b128 is wave-sequential 1KB -> zero bank conflicts.
// ---------------------------------------------------------------------------

typedef __bf16 bf16;
using i32x4 = __attribute__((ext_vector_type(4))) int;

#define NT     64
#define BATCH  512

#define OFF_XQH 0ul
#define OFF_XQL 33554432ul
#define OFF_WT  67108864ul
#define OFF_K   70254592ul
#define OFF_Q   137363456ul
#define OFF_V   204472320ul
#define OFF_AW  271581184ul
#define OFF_MS  279969792ul

// ---------------------------------------------------------------------------
__global__ void quant_kernel(const float* __restrict__ x,
                             unsigned int* __restrict__ qh,
                             unsigned int* __restrict__ ql, int n4, float invS) {
  int i = blockIdx.x * blockDim.x + threadIdx.x;
  int stride = gridDim.x * blockDim.x;
  for (; i < n4; i += stride) {
    float4 v = ((const float4*)x)[i];
    unsigned hw = 0, lw = 0;
#pragma unroll
    for (int j = 0; j < 4; ++j) {
      float f = (j == 0) ? v.x : (j == 1) ? v.y : (j == 2) ? v.z : v.w;
      int q = __float2int_rn(f * invS);
      q = max(-16320, min(16319, q));
      int h = (q + 64) >> 7;
      int lo = q - (h << 7);
      hw |= ((unsigned)(h & 0xFF)) << (8 * j);
      lw |= ((unsigned)(lo & 0xFF)) << (8 * j);
    }
    qh[i] = hw;
    ql[i] = lw;
  }
}

// ---------------------------------------------------------------------------
// quantize W into fragment-tiled layout (all 3 projections in one launch):
//   WT[proj] : offset = ((ct*16 + kc)*2048) + plane*1024 + lane*16 + ki
//   ct = c>>4, kc = k>>6, lane = (c&15) | (((k>>4)&3)<<4), ki = k&15.
// ---------------------------------------------------------------------------
__global__ void quant_w_kernel(const float* __restrict__ W0,
                               const float* __restrict__ W1,
                               const float* __restrict__ W2,
                               char* __restrict__ WT, float invS) {
  int gid = blockIdx.x * blockDim.x + threadIdx.x;  // 0..393215
  int proj = gid >> 17;
  int idx = gid & 131071;
  const float* W = (proj == 0) ? W0 : (proj == 1 ? W1 : W2);
  int c = idx >> 8, k = (idx & 255) * 4;
  float4 v = ((const float4*)W)[idx];
  unsigned hw = 0, lw = 0;
#pragma unroll
  for (int j = 0; j < 4; ++j) {
    float f = (j == 0) ? v.x : (j == 1) ? v.y : (j == 2) ? v.z : v.w;
    int q = __float2int_rn(f * invS);
    q = max(-16320, min(16319, q));
    int h = (q + 64) >> 7;
    int lo = q - (h << 7);
    hw |= ((unsigned)(h & 0xFF)) << (8 * j);
    lw |= ((unsigned)(lo & 0xFF)) << (8 * j);
  }
  int kc = k >> 6, kg = (k >> 4) & 3, ki = k & 15;
  int ct = c >> 4, lane = (c & 15) | (kg << 4);
  size_t dst = (size_t)proj * 1048576 + (size_t)(ct * 16 + kc) * 2048 +
               lane * 16 + ki;
  *(unsigned int*)(WT + dst) = hw;          // ph plane
  *(unsigned int*)(WT + dst + 1024) = lw;   // pl plane
}

// ---------------------------------------------------------------------------
__device__ __forceinline__ void gl16(const char* g, char* l) {
  __builtin_amdgcn_global_load_lds(
      (const __attribute__((address_space(1))) unsigned int*)g,
      (__attribute__((address_space(3))) unsigned int*)l, 16, 0, 0);
}

#define VMCNT0 asm volatile("s_waitcnt vmcnt(0)" ::: "memory")
#define BAR    __builtin_amdgcn_s_barrier()

__global__ __launch_bounds__(512, 2) void gemm_i8(
    const char* __restrict__ XQH, const char* __restrict__ XQL,
    const char* __restrict__ WT,
    const float* __restrict__ bk, const float* __restrict__ bq,
    const float* __restrict__ bv,
    float* __restrict__ K, float* __restrict__ Q, float* __restrict__ V) {
  __shared__ __align__(16) char lds[98304];  // 2 x 48KB
  // per-buffer: A qh [0,8K), A ql [8K,16K), B [16K,48K) = 16 ct x 2KB(ph|pl)

  // T1: bijective XCD swizzle (1536 = 8 * 192)
  const int bid = (blockIdx.x & 7) * 192 + (blockIdx.x >> 3);
  const int mt = bid / 6, ntb = bid % 6;
  const int gm0 = mt * 128;
  const int proj = ntb >> 1;
  const int wn0 = (ntb & 1) * 256;

  const int tid = threadIdx.x;
  const int l = tid & 63, w = tid >> 6;
  const int wr = w >> 2, wc = w & 3;  // 2M x 4N waves, wave tile 64x64
  const int lr = l & 15, lk = l >> 4;

  // A staging: thread tid stages 16B/plane/chunk in fragment order.
  const int srow = ((tid >> 6) << 4) | (tid & 15);
  const int skk = ((tid >> 4) & 3) << 4;
  const char* aqh = XQH + (size_t)(gm0 + srow) * 1024 + skk;
  const char* aql = XQL + (size_t)(gm0 + srow) * 1024 + skk;
  // B staging: 4 x 16B/thread from pre-tiled WT (already fragment-order).
  const char* wB = WT + (size_t)proj * 1048576 +
                   (size_t)((ntb & 1) * 16 + (tid >> 7)) * 32768 +
                   (tid & 127) * 16;
  const int dT = tid * 16;

  // fragment read offsets (wave-sequential 1KB each -> conflict-free)
  const int rdA = wr * 4096 + l * 16;            // + mf*1024 (+8192 for ql)
  const int rdB = 16384 + wc * 8192 + l * 16;    // + nf*2048 (+1024 for pl)

  i32x4 acc1[4][4] = {};
  i32x4 acc2[4][4] = {};

  auto STAGE = [&](int kc, int bo) {
    const int kA = kc * 64, kB = kc * 2048;
    gl16(aqh + kA, lds + bo + dT);
    gl16(aql + kA, lds + bo + 8192 + dT);
    gl16(wB + kB, lds + bo + 16384 + dT);
    gl16(wB + kB + 131072, lds + bo + 24576 + dT);
    gl16(wB + kB + 262144, lds + bo + 32768 + dT);
    gl16(wB + kB + 393216, lds + bo + 40960 + dT);
  };

  STAGE(0, 0);

  for (int kc = 0; kc < 16; ++kc) {
    const int bo = (kc & 1) * 49152;
    VMCNT0;  // own chunk-kc stages done (issued a full chunk ago)
    BAR;     // all waves' stages landed; prev-chunk reads all retired
    if (kc < 15) STAGE(kc + 1, bo ^ 49152);

    i32x4 aH[4], aL[4], bH[4], bL[4];
#pragma unroll
    for (int mf = 0; mf < 4; ++mf)
      aH[mf] = *(const i32x4*)(lds + bo + rdA + mf * 1024);
#pragma unroll
    for (int nf = 0; nf < 4; ++nf)
      bL[nf] = *(const i32x4*)(lds + bo + rdB + nf * 2048 + 1024);

    __builtin_amdgcn_s_setprio(1);
#pragma unroll
    for (int mf = 0; mf < 4; ++mf)   // alpha: qh . pl -> acc2
#pragma unroll
      for (int nf = 0; nf < 4; ++nf)
        acc2[mf][nf] = __builtin_amdgcn_mfma_i32_16x16x64_i8(
            aH[mf], bL[nf], acc2[mf][nf], 0, 0, 0);
    __builtin_amdgcn_s_setprio(0);

#pragma unroll
    for (int nf = 0; nf < 4; ++nf)
      bH[nf] = *(const i32x4*)(lds + bo + rdB + nf * 2048);

    __builtin_amdgcn_s_setprio(1);
#pragma unroll
    for (int mf = 0; mf < 4; ++mf)   // beta: qh . ph -> acc1 (reuse aH)
#pragma unroll
      for (int nf = 0; nf < 4; ++nf)
        acc1[mf][nf] = __builtin_amdgcn_mfma_i32_16x16x64_i8(
            aH[mf], bH[nf], acc1[mf][nf], 0, 0, 0);
    __builtin_amdgcn_s_setprio(0);

#pragma unroll
    for (int mf = 0; mf < 4; ++mf)
      aL[mf] = *(const i32x4*)(lds + bo + 8192 + rdA + mf * 1024);

    __builtin_amdgcn_s_setprio(1);
#pragma unroll
    for (int mf = 0; mf < 4; ++mf)   // gamma: ql . ph -> acc2 (reuse bH)
#pragma unroll
      for (int nf = 0; nf < 4; ++nf)
        acc2[mf][nf] = __builtin_amdgcn_mfma_i32_16x16x64_i8(
            aL[mf], bH[nf], acc2[mf][nf], 0, 0, 0);
    __builtin_amdgcn_s_setprio(0);
  }

  // epilogue: Out = XS*WS*(16384*acc1 + 128*acc2) + bias
  const float SC = (6.0f / 16256.0f) * (0.03125f / 16320.0f);
  const float* bias = (proj == 0) ? bk : (proj == 1 ? bq : bv);
  float* Out = (proj == 0) ? K : (proj == 1 ? Q : V);
#pragma unroll
  for (int mf = 0; mf < 4; ++mf) {
    const int row0 = gm0 + wr * 64 + mf * 16 + lk * 4;
#pragma unroll
    for (int nf = 0; nf < 4; ++nf) {
      const int col = wn0 + wc * 64 + nf * 16 + lr;
      const float bb = bias[col];
#pragma unroll
      for (int r = 0; r < 4; ++r)
        Out[(size_t)(row0 + r) * 512 + col] =
            fmaf(16384.f, (float)acc1[mf][nf][r],
                 128.f * (float)acc2[mf][nf][r]) * SC + bb;
    }
  }
}

// ---------------------------------------------------------------------------
// logits: AW[b,t,s] = (1/sqrt(512)) * sum_c K[b*64+t,c] * Q[b*64+s,c]
// ---------------------------------------------------------------------------
__global__ __launch_bounds__(256) void logits_kernel(
    const float* __restrict__ K, const float* __restrict__ Q,
    float* __restrict__ AW) {
  __shared__ float Ks[64][68];
  __shared__ float Qs[64][68];
  const int b = blockIdx.x;
  const float* Kb = K + (size_t)b * 32768;
  const float* Qb = Q + (size_t)b * 32768;
  const int tid = threadIdx.x;
  const int tr = tid >> 4, tc = tid & 15;

  float acc[4][4] = {};
  for (int c0 = 0; c0 < 512; c0 += 64) {
    __syncthreads();
#pragma unroll
    for (int i = 0; i < 4; ++i) {
      int idx = tid + i * 256;
      int row = idx >> 4;
      int c4 = (idx & 15) * 4;
      float4 kv = *(const float4*)&Kb[row * 512 + c0 + c4];
      float4 qv = *(const float4*)&Qb[row * 512 + c0 + c4];
      Ks[c4 + 0][row] = kv.x; Ks[c4 + 1][row] = kv.y;
      Ks[c4 + 2][row] = kv.z; Ks[c4 + 3][row] = kv.w;
      Qs[c4 + 0][row] = qv.x; Qs[c4 + 1][row] = qv.y;
      Qs[c4 + 2][row] = qv.z; Qs[c4 + 3][row] = qv.w;
    }
    __syncthreads();
#pragma unroll 4
    for (int cc = 0; cc < 64; ++cc) {
      float4 kx = *(const float4*)&Ks[cc][tr * 4];
      float4 qx = *(const float4*)&Qs[cc][tc * 4];
#pragma unroll
      for (int i = 0; i < 4; ++i)
#pragma unroll
        for (int j = 0; j < 4; ++j) acc[i][j] += kx[i] * qx[j];
    }
  }
  const float scale = 0.04419417382415922f;
#pragma unroll
  for (int i = 0; i < 4; ++i)
#pragma unroll
    for (int j = 0; j < 4; ++j)
      AW[(size_t)b * 4096 + (tr * 4 + i) * 64 + (tc * 4 + j)] =
          acc[i][j] * scale;
}

// ---------------------------------------------------------------------------
// stats over batch axis: for each (t,s), m = max_b, inv = 1/sum_b exp(l-m).
// ---------------------------------------------------------------------------
__global__ __launch_bounds__(1024) void stats_kernel(
    const float* __restrict__ AW, float* __restrict__ M,
    float* __restrict__ I) {
  __shared__ float red[16][64];
  const int tt = blockIdx.x;
  const int tid = threadIdx.x;
  const int s = tid & 63, bq = tid >> 6;
  const size_t base = (size_t)tt * 64 + s;

  float m = -3.4e38f;
  for (int b = bq * 32; b < bq * 32 + 32; ++b)
    m = fmaxf(m, AW[(size_t)b * 4096 + base]);
  red[bq][s] = m;
  __syncthreads();
#pragma unroll
  for (int i = 0; i < 16; ++i) m = fmaxf(m, red[i][s]);
  __syncthreads();

  float sum = 0.f;
  for (int b = bq * 32; b < bq * 32 + 32; ++b)
    sum += __expf(AW[(size_t)b * 4096 + base] - m);
  red[bq][s] = sum;
  __syncthreads();
  if (bq == 0) {
    sum = 0.f;
#pragma unroll
    for (int i = 0; i < 16; ++i) sum += red[i][s];
    M[tt * 64 + s] = m;
    I[tt * 64 + s] = 1.0f / sum;
  }
}

// ---------------------------------------------------------------------------
// out[b,c,s] = sum_t V[b*64+t, c] * p,  p = exp(AW[b,t,s]-M[t,s])*I[t,s]
// ---------------------------------------------------------------------------
__global__ __launch_bounds__(256) void out_kernel(
    const float* __restrict__ V, const float* __restrict__ AW,
    const float* __restrict__ M, const float* __restrict__ I,
    float* __restrict__ out) {
  __shared__ float Ps[64][68];
  __shared__ float Vs[64][68];
  const int b = blockIdx.x;
  const int tid = threadIdx.x;
  const float* Pb = AW + (size_t)b * 4096;
  for (int i = tid; i < 4096; i += 256)
    Ps[i >> 6][i & 63] = __expf(Pb[i] - M[i]) * I[i];

  const int s = tid & 63, cw = tid >> 6;
  const float* Vb = V + (size_t)b * 32768;
  float* Ob = out + (size_t)b * 32768;

  for (int ch = 0; ch < 8; ++ch) {
    __syncthreads();
    for (int i = tid; i < 1024; i += 256) {
      int row = i >> 4, c4 = (i & 15) * 4;
      float4 v = *(const float4*)&Vb[(size_t)row * 512 + ch * 64 + c4];
      Vs[row][c4 + 0] = v.x; Vs[row][c4 + 1] = v.y;
      Vs[row][c4 + 2] = v.z; Vs[row][c4 + 3] = v.w;
    }
    __syncthreads();
    float a[16] = {};
    for (int t = 0; t < 64; ++t) {
      float p = Ps[t][s];
      float4 v0 = *(const float4*)&Vs[t][cw * 16 + 0];
      float4 v1 = *(const float4*)&Vs[t][cw * 16 + 4];
      float4 v2 = *(const float4*)&Vs[t][cw * 16 + 8];
      float4 v3 = *(const float4*)&Vs[t][cw * 16 + 12];
#pragma unroll
      for (int j = 0; j < 4; ++j) {
        a[j + 0] += v0[j] * p; a[j + 4] += v1[j] * p;
        a[j + 8] += v2[j] * p; a[j + 12] += v3[j] * p;
      }
    }
#pragma unroll
    for (int j = 0; j < 16; ++j)
      Ob[(size_t)(ch * 64 + cw * 16 + j) * 64 + s] = a[j];
  }
}

// ---------------------------------------------------------------------------
extern "C" void kernel_launch(void* const* d_in, const int* in_sizes, int n_in,
                              void* d_out, int out_size, void* d_ws,
                              size_t ws_size, hipStream_t stream) {
  const float* x  = (const float*)d_in[0];
  const float* Wk = (const float*)d_in[1];
  const float* bk = (const float*)d_in[2];
  const float* Wq = (const float*)d_in[3];
  const float* bq = (const float*)d_in[4];
  const float* Wv = (const float*)d_in[5];
  const float* bv = (const float*)d_in[6];
  float* out = (float*)d_out;

  char* ws = (char*)d_ws;
  unsigned int* XQH = (unsigned int*)(ws + OFF_XQH);
  unsigned int* XQL = (unsigned int*)(ws + OFF_XQL);
  char* WT = ws + OFF_WT;
  float* K  = (float*)(ws + OFF_K);
  float* Q  = (float*)(ws + OFF_Q);
  float* V  = (float*)(ws + OFF_V);
  float* AW = (float*)(ws + OFF_AW);
  float* M  = (float*)(ws + OFF_MS);
  float* I  = (float*)(ws + OFF_MS + 16384);

  const float invXS = 16256.0f / 6.0f;
  const float invWS = 16320.0f / 0.03125f;

  quant_kernel<<<2048, 256, 0, stream>>>(x, XQH, XQL, 8388608, invXS);
  quant_w_kernel<<<1536, 256, 0, stream>>>(Wk, Wq, Wv, WT, invWS);

  gemm_i8<<<1536, 512, 0, stream>>>((const char*)XQH, (const char*)XQL,
                                    WT, bk, bq, bv, K, Q, V);

  logits_kernel<<<BATCH, 256, 0, stream>>>(K, Q, AW);
  stats_kernel<<<NT, 1024, 0, stream>>>(AW, M, I);
  out_kernel<<<BATCH, 256, 0, stream>>>(V, AW, M, I, out);
}